// Round 10
// baseline (146.621 us; speedup 1.0000x reference)
//
#include <hip/hip_runtime.h>

// TopologyNetwork: B=1024, N=5000, K=16, 9 levels.
// R10 = R9 (fully-fused LDS ping-pong) + bank-conflict scheduling:
//  - k-sum is commutative: at pack time, each node's 16 edges are bucket-
//    sorted by LDS bank class (s%16) and rotated by lane%16, so at step k
//    the 64 lanes of a wave hit classes ~(l+k)%16 -> ~4 accesses/bank pair
//    (the ds_read_b64 floor) instead of random max ~9-10.
//  - packed edge u32 = (s*8 low16 | f16 w high16): LDS byte offset direct.
//  - k_pack: one wave per (level, panel-of-64-nodes); coalesced pe writes.

#define TB 1024
#define TN 5000
#define TK 16
#define TLV 9
#define CPG 4                   // f16 cols per group (8 B per node-row)
#define NG  (TB / CPG)          // 256 col-groups = grid
#define LT  1024                // threads per block (16 waves)
#define NPANEL ((TN + 63) / 64) // 79 panels of 64 nodes
#define PEL (NPANEL * TK * 64)  // u32 per level in packed-edge array

typedef unsigned int u32;
typedef unsigned short u16;
typedef _Float16 h2 __attribute__((ext_vector_type(2)));

__device__ __forceinline__ h2 u2h(u32 v) { return __builtin_bit_cast(h2, v); }
__device__ __forceinline__ u32 h2u(h2 h) { return __builtin_bit_cast(u32, h); }
__device__ __forceinline__ u32 packf(float a, float b) {
    h2 h; h.x = (_Float16)a; h.y = (_Float16)b;
    return h2u(h);
}

// ---- pack + schedule edges ----
// idx i32 + w f32 [l][n][k]  ->  pe u32 [l][panel][k][lane],
// each node's edges bucket-sorted by bank class (s%16), rotated by lane%16.
__global__ __launch_bounds__(256) void k_pack(
    const int* __restrict__ idx, const float* __restrict__ w,
    u32* __restrict__ pe)
{
    const int wid  = (blockIdx.x * 256 + threadIdx.x) >> 6;  // global wave id
    const int lane = threadIdx.x & 63;
    const int l = wid / NPANEL;
    const int p = wid % NPANEL;
    if (l >= TLV) return;
    const int n = p * 64 + lane;

    u32 ev[TK];
    if (n < TN) {
        const size_t base = ((size_t)l * TN + n) * TK;
        #pragma unroll
        for (int k = 0; k < TK; ++k) {
            const u32 s = (u32)idx[base + k];
            h2 hw; hw.x = (_Float16)w[base + k]; hw.y = (_Float16)0.0f;
            ev[k] = (s * 8u) | (h2u(hw) << 16);   // low16 = LDS byte offset
        }
    } else {
        #pragma unroll
        for (int k = 0; k < TK; ++k) ev[k] = 0;
    }

    // selection-sort 16 elems by bank class ((s*8)>>3)&15 == s%16
    for (int i = 0; i < TK - 1; ++i) {
        int m = i;
        for (int j = i + 1; j < TK; ++j)
            if (((ev[j] >> 3) & 15u) < ((ev[m] >> 3) & 15u)) m = j;
        u32 t = ev[i]; ev[i] = ev[m]; ev[m] = t;
    }

    // rotate by lane%16, write [k][lane] (lane-contiguous -> coalesced)
    const u32 rot = (u32)(lane & 15);
    u32* dst = pe + (size_t)l * PEL + (size_t)p * (TK * 64) + lane;
    for (int k = 0; k < TK; ++k)
        dst[k * 64] = ev[(k + rot) & 15u];
}

// ---- fused: transpose-in + 9 levels in LDS + transpose-out ----
__global__ __launch_bounds__(LT) void k_fused(
    const float* __restrict__ x,      // [B,N]
    float* __restrict__ out,          // [B,N]
    const u32* __restrict__ pe,       // [LV][PEL]
    const float* __restrict__ biases) // [LV][TN]
{
    __shared__ uint2 buf[2][TN];      // 2 x 40000 B ping-pong
    const int g = blockIdx.x;
    const int t = threadIdx.x;

    // stage x cols g*4..g*4+3 as f16 rows
    {
        const float* xp0 = x + (size_t)(g * CPG + 0) * TN;
        const float* xp1 = x + (size_t)(g * CPG + 1) * TN;
        const float* xp2 = x + (size_t)(g * CPG + 2) * TN;
        const float* xp3 = x + (size_t)(g * CPG + 3) * TN;
        for (int n = t; n < TN; n += LT) {
            uint2 v;
            v.x = packf(xp0[n], xp1[n]);
            v.y = packf(xp2[n], xp3[n]);
            buf[0][n] = v;
        }
    }
    __syncthreads();

    int cur = 0;
    for (int l = 0; l < TLV; ++l) {
        const u32*   ep_l = pe + (size_t)l * PEL;
        const float* b_l  = biases + (size_t)l * TN;
        const char*  base = reinterpret_cast<const char*>(buf[cur]);
        for (int n = t; n < TN; n += LT) {
            const u32* ep = ep_l + (n >> 6) * (TK * 64) + (n & 63);
            const float bvf = b_l[n];
            h2 bb; bb.x = (_Float16)bvf; bb.y = (_Float16)bvf;
            h2 a01 = bb, a23 = bb;

            #pragma unroll
            for (int k = 0; k < TK; ++k) {
                const u32 e  = ep[k * 64];                 // coalesced 256 B line
                const u32 s8 = e & 0xffffu;                // LDS byte offset
                const h2 w2 = u2h(__builtin_amdgcn_perm(e, e, 0x03020302u));
                const uint2 av = *reinterpret_cast<const uint2*>(base + s8);
                a01 = w2 * u2h(av.x) + a01;                // v_pk_fma_f16
                a23 = w2 * u2h(av.y) + a23;
            }

            // LeakyReLU(0.1) = max(x, 0.1*x)
            h2 tenth; tenth.x = (_Float16)0.1f; tenth.y = (_Float16)0.1f;
            a01 = __builtin_elementwise_max(a01, a01 * tenth);
            a23 = __builtin_elementwise_max(a23, a23 * tenth);

            uint2 r; r.x = h2u(a01); r.y = h2u(a23);
            buf[cur ^ 1][n] = r;
        }
        __syncthreads();
        cur ^= 1;
    }

    // write out cols g*4..g*4+3
    {
        float* op0 = out + (size_t)(g * CPG + 0) * TN;
        float* op1 = out + (size_t)(g * CPG + 1) * TN;
        float* op2 = out + (size_t)(g * CPG + 2) * TN;
        float* op3 = out + (size_t)(g * CPG + 3) * TN;
        for (int n = t; n < TN; n += LT) {
            const uint2 v = buf[cur][n];
            h2 h;
            h = u2h(v.x); op0[n] = (float)h.x; op1[n] = (float)h.y;
            h = u2h(v.y); op2[n] = (float)h.x; op3[n] = (float)h.y;
        }
    }
}

extern "C" void kernel_launch(void* const* d_in, const int* in_sizes, int n_in,
                              void* d_out, int out_size, void* d_ws, size_t ws_size,
                              hipStream_t stream)
{
    const float* x       = (const float*)d_in[0];   // [B,N]
    const int*   src_idx = (const int*)  d_in[1];   // [LV,N,K]
    const float* weights = (const float*)d_in[2];   // [LV,N,K]
    const float* biases  = (const float*)d_in[3];   // [LV,N]
    float* out = (float*)d_out;                     // [B,N]

    u32* pe = (u32*)d_ws;                           // [LV][PEL] = 2.91 MB

    // pack + schedule edges: one wave per (level, panel)
    {
        const int nwaves  = TLV * NPANEL;           // 711
        const int nblocks = (nwaves + 3) / 4;       // 4 waves per 256-thr block
        hipLaunchKernelGGL(k_pack, dim3(nblocks), dim3(256), 0, stream,
                           src_idx, weights, pe);
    }
    // fused 9-level evaluation
    hipLaunchKernelGGL(k_fused, dim3(NG), dim3(LT), 0, stream,
                       x, out, pe, biases);
}

// Round 11
// 128.607 us; speedup vs baseline: 1.1401x; 1.1401x over previous
//
#include <hip/hip_runtime.h>

// TopologyNetwork: B=1024, N=5000, K=16, 9 levels.
// R11 = R9 fused structure + R10's bank-aware edge order, with k_pack fixed:
//  - R10's selection sort used dynamic register indexing -> scratch spills
//    (~42 us pack). Replaced with a STATIC odd-even transposition network
//    (120 compare-exchanges, all indices compile-time -> stays in VGPRs).
//  - rotation by lane%16 moved to the STORE side: slot ((r-lane)&15) gets
//    rank-r edge; store address is dynamic (fine), register index static.
//  - k_fused unchanged: fully-fused 9 levels ping-ponging in 2x40KB LDS,
//    edges prepacked [l][panel64][k][lane] u32 = (s*8 | f16 w << 16).

#define TB 1024
#define TN 5000
#define TK 16
#define TLV 9
#define CPG 4                   // f16 cols per group (8 B per node-row)
#define NG  (TB / CPG)          // 256 col-groups = grid
#define LT  1024                // threads per block (16 waves)
#define NPANEL ((TN + 63) / 64) // 79 panels of 64 nodes
#define PEL (NPANEL * TK * 64)  // u32 per level in packed-edge array

typedef unsigned int u32;
typedef unsigned short u16;
typedef _Float16 h2 __attribute__((ext_vector_type(2)));

__device__ __forceinline__ h2 u2h(u32 v) { return __builtin_bit_cast(h2, v); }
__device__ __forceinline__ u32 h2u(h2 h) { return __builtin_bit_cast(u32, h); }
__device__ __forceinline__ u32 packf(float a, float b) {
    h2 h; h.x = (_Float16)a; h.y = (_Float16)b;
    return h2u(h);
}

// ---- pack + schedule edges ----
// idx i32 + w f32 [l][n][k] -> pe u32 [l][panel][slot][lane];
// per node: sort edges by bank class (s%16) with a static network, then
// slot = (rank - lane) & 15 so step k reads rank (k+lane)&15 -> classes
// de-correlated across lanes.
__global__ __launch_bounds__(256) void k_pack(
    const int* __restrict__ idx, const float* __restrict__ w,
    u32* __restrict__ pe)
{
    const int wid  = (blockIdx.x * 256 + threadIdx.x) >> 6;  // global wave id
    const int lane = threadIdx.x & 63;
    const int l = wid / NPANEL;
    const int p = wid % NPANEL;
    if (l >= TLV) return;
    const int n = p * 64 + lane;

    u32 ev[TK];
    if (n < TN) {
        const size_t base = ((size_t)l * TN + n) * TK;
        #pragma unroll
        for (int k = 0; k < TK; ++k) {
            const u32 s = (u32)idx[base + k];
            h2 hw; hw.x = (_Float16)w[base + k]; hw.y = (_Float16)0.0f;
            ev[k] = (s * 8u) | (h2u(hw) << 16);   // low16 = LDS byte offset
        }
    } else {
        #pragma unroll
        for (int k = 0; k < TK; ++k) ev[k] = 0;
    }

    // odd-even transposition sort by bank class ((e>>3)&15); static indices
    #pragma unroll
    for (int round = 0; round < TK; ++round) {
        const int start = round & 1;
        #pragma unroll
        for (int i = start; i + 1 < TK; i += 2) {
            const u32 a = ev[i], b = ev[i + 1];
            const bool swp = ((b >> 3) & 15u) < ((a >> 3) & 15u);
            ev[i]     = swp ? b : a;
            ev[i + 1] = swp ? a : b;
        }
    }

    // slot ((r - lane) & 15) <- rank r  (register index static, addr dynamic)
    u32* dst = pe + (size_t)l * PEL + (size_t)p * (TK * 64) + lane;
    const int rot = lane & 15;
    #pragma unroll
    for (int r = 0; r < TK; ++r)
        dst[((r - rot) & 15) * 64] = ev[r];
}

// ---- fused: transpose-in + 9 levels in LDS + transpose-out ----
__global__ __launch_bounds__(LT) void k_fused(
    const float* __restrict__ x,      // [B,N]
    float* __restrict__ out,          // [B,N]
    const u32* __restrict__ pe,       // [LV][PEL]
    const float* __restrict__ biases) // [LV][TN]
{
    __shared__ uint2 buf[2][TN];      // 2 x 40000 B ping-pong
    const int g = blockIdx.x;
    const int t = threadIdx.x;

    // stage x cols g*4..g*4+3 as f16 rows
    {
        const float* xp0 = x + (size_t)(g * CPG + 0) * TN;
        const float* xp1 = x + (size_t)(g * CPG + 1) * TN;
        const float* xp2 = x + (size_t)(g * CPG + 2) * TN;
        const float* xp3 = x + (size_t)(g * CPG + 3) * TN;
        for (int n = t; n < TN; n += LT) {
            uint2 v;
            v.x = packf(xp0[n], xp1[n]);
            v.y = packf(xp2[n], xp3[n]);
            buf[0][n] = v;
        }
    }
    __syncthreads();

    int cur = 0;
    for (int l = 0; l < TLV; ++l) {
        const u32*   ep_l = pe + (size_t)l * PEL;
        const float* b_l  = biases + (size_t)l * TN;
        const char*  base = reinterpret_cast<const char*>(buf[cur]);
        for (int n = t; n < TN; n += LT) {
            const u32* ep = ep_l + (n >> 6) * (TK * 64) + (n & 63);
            const float bvf = b_l[n];
            h2 bb; bb.x = (_Float16)bvf; bb.y = (_Float16)bvf;
            h2 a01 = bb, a23 = bb;

            #pragma unroll
            for (int k = 0; k < TK; ++k) {
                const u32 e  = ep[k * 64];                 // coalesced 256 B line
                const u32 s8 = e & 0xffffu;                // LDS byte offset
                const h2 w2 = u2h(__builtin_amdgcn_perm(e, e, 0x03020302u));
                const uint2 av = *reinterpret_cast<const uint2*>(base + s8);
                a01 = w2 * u2h(av.x) + a01;                // v_pk_fma_f16
                a23 = w2 * u2h(av.y) + a23;
            }

            // LeakyReLU(0.1) = max(x, 0.1*x)
            h2 tenth; tenth.x = (_Float16)0.1f; tenth.y = (_Float16)0.1f;
            a01 = __builtin_elementwise_max(a01, a01 * tenth);
            a23 = __builtin_elementwise_max(a23, a23 * tenth);

            uint2 r; r.x = h2u(a01); r.y = h2u(a23);
            buf[cur ^ 1][n] = r;
        }
        __syncthreads();
        cur ^= 1;
    }

    // write out cols g*4..g*4+3
    {
        float* op0 = out + (size_t)(g * CPG + 0) * TN;
        float* op1 = out + (size_t)(g * CPG + 1) * TN;
        float* op2 = out + (size_t)(g * CPG + 2) * TN;
        float* op3 = out + (size_t)(g * CPG + 3) * TN;
        for (int n = t; n < TN; n += LT) {
            const uint2 v = buf[cur][n];
            h2 h;
            h = u2h(v.x); op0[n] = (float)h.x; op1[n] = (float)h.y;
            h = u2h(v.y); op2[n] = (float)h.x; op3[n] = (float)h.y;
        }
    }
}

extern "C" void kernel_launch(void* const* d_in, const int* in_sizes, int n_in,
                              void* d_out, int out_size, void* d_ws, size_t ws_size,
                              hipStream_t stream)
{
    const float* x       = (const float*)d_in[0];   // [B,N]
    const int*   src_idx = (const int*)  d_in[1];   // [LV,N,K]
    const float* weights = (const float*)d_in[2];   // [LV,N,K]
    const float* biases  = (const float*)d_in[3];   // [LV,N]
    float* out = (float*)d_out;                     // [B,N]

    u32* pe = (u32*)d_ws;                           // [LV][PEL] = 2.91 MB

    // pack + schedule edges: one wave per (level, panel)
    {
        const int nwaves  = TLV * NPANEL;           // 711
        const int nblocks = (nwaves + 3) / 4;       // 4 waves per 256-thr block
        hipLaunchKernelGGL(k_pack, dim3(nblocks), dim3(256), 0, stream,
                           src_idx, weights, pe);
    }
    // fused 9-level evaluation
    hipLaunchKernelGGL(k_fused, dim3(NG), dim3(LT), 0, stream,
                       x, out, pe, biases);
}